// Round 1
// baseline (553.976 us; speedup 1.0000x reference)
//
#include <hip/hip_runtime.h>

#define DIM 1024
#define HEADS 16
#define HEAD_DIM 64
#define HIDDEN 4096
#define BB 2
#define NN 2048
#define TOK (BB*NN)          // 4096 rows

typedef __attribute__((ext_vector_type(8))) short bf16x8;
typedef __attribute__((ext_vector_type(4))) float f32x4;

__device__ inline short f2bf(float f) {
    unsigned u = __float_as_uint(f);
    unsigned r = (u + 0x7fff + ((u >> 16) & 1)) >> 16;
    return (short)r;
}

#define GLL16(g, l)                                                          \
    __builtin_amdgcn_global_load_lds(                                        \
        (const __attribute__((address_space(1))) void*)(g),                  \
        (__attribute__((address_space(3))) void*)(l), 16, 0, 0)

// ---------------- fp32 -> bf16 convert ----------------
__global__ void cvt_kernel(const float* __restrict__ in, short* __restrict__ out, int n4) {
    int i = blockIdx.x * blockDim.x + threadIdx.x;
    int stride = gridDim.x * blockDim.x;
    for (; i < n4; i += stride) {
        float4 v = ((const float4*)in)[i];
        short4 o;
        o.x = f2bf(v.x); o.y = f2bf(v.y); o.z = f2bf(v.z); o.w = f2bf(v.w);
        ((short4*)out)[i] = o;
    }
}

// ---------------- LayerNorm (per-row, DIM=1024) -> bf16 ----------------
__global__ __launch_bounds__(256) void ln_kernel(const float* __restrict__ x,
                                                 const float* __restrict__ w,
                                                 const float* __restrict__ b,
                                                 short* __restrict__ out) {
    const int row = blockIdx.x;
    const int t = threadIdx.x;
    float4 v = ((const float4*)(x + (long)row * DIM))[t];
    float s = v.x + v.y + v.z + v.w;
    float ss = v.x * v.x + v.y * v.y + v.z * v.z + v.w * v.w;
#pragma unroll
    for (int m = 1; m < 64; m <<= 1) {
        s += __shfl_xor(s, m);
        ss += __shfl_xor(ss, m);
    }
    __shared__ float rs[4], rss[4];
    int wv = t >> 6;
    if ((t & 63) == 0) { rs[wv] = s; rss[wv] = ss; }
    __syncthreads();
    s = rs[0] + rs[1] + rs[2] + rs[3];
    ss = rss[0] + rss[1] + rss[2] + rss[3];
    float mean = s * (1.f / DIM);
    float var = ss * (1.f / DIM) - mean * mean;
    float rstd = rsqrtf(var + 1e-5f);
    float4 wv4 = ((const float4*)w)[t];
    float4 bv4 = ((const float4*)b)[t];
    short4 o;
    o.x = f2bf((v.x - mean) * rstd * wv4.x + bv4.x);
    o.y = f2bf((v.y - mean) * rstd * wv4.y + bv4.y);
    o.z = f2bf((v.z - mean) * rstd * wv4.z + bv4.z);
    o.w = f2bf((v.w - mean) * rstd * wv4.w + bv4.w);
    ((short4*)(out + (long)row * DIM))[t] = o;
}

// ---------------- GEMM: C[M,N] = A[M,K] @ Bt[N,K]^T + bias ----------------
// EPI: 0 plain bf16 out; 1 qkv (scale cols<DIM by 0.125, bf16 out);
//      2 gelu bf16 out; 3 residual+layer-scale fp32 out
template <int EPI>
__global__ __launch_bounds__(256) void gemm_bt(const short* __restrict__ A,
                                               const short* __restrict__ Bt,
                                               const float* __restrict__ bias,
                                               const float* __restrict__ resid,
                                               const float* __restrict__ gamma,
                                               void* __restrict__ Cout,
                                               int M, int N, int K) {
    __shared__ __align__(16) short As[128 * 32];
    __shared__ __align__(16) short Bs[128 * 32];
    const int t = threadIdx.x;
    const int w = t >> 6, l = t & 63, lr = l & 15, lg = l >> 4;
    const int wr = w >> 1, wc = w & 1;
    const int rowBase = blockIdx.y * 128, colBase = blockIdx.x * 128;

    f32x4 acc[4][4];
#pragma unroll
    for (int m = 0; m < 4; m++)
#pragma unroll
        for (int n = 0; n < 4; n++) acc[m][n] = {0.f, 0.f, 0.f, 0.f};

    for (int k0 = 0; k0 < K; k0 += 32) {
        __syncthreads();
#pragma unroll
        for (int r = 0; r < 2; r++) {
            int c = r * 256 + t;
            int row = c >> 2, col = (c & 3) * 8;
            const short* ga = A + (long)(rowBase + row) * K + k0 + col;
            const short* gb = Bt + (long)(colBase + row) * K + k0 + col;
            int ldsoff = (r * 256 + w * 64) * 8;
            GLL16(ga, As + ldsoff);
            GLL16(gb, Bs + ldsoff);
        }
        __syncthreads();
        bf16x8 af[4], bfr[4];
#pragma unroll
        for (int m = 0; m < 4; m++)
            af[m] = *(const bf16x8*)&As[(wr * 64 + m * 16 + lr) * 32 + lg * 8];
#pragma unroll
        for (int n = 0; n < 4; n++)
            bfr[n] = *(const bf16x8*)&Bs[(wc * 64 + n * 16 + lr) * 32 + lg * 8];
#pragma unroll
        for (int m = 0; m < 4; m++)
#pragma unroll
            for (int n = 0; n < 4; n++)
                acc[m][n] = __builtin_amdgcn_mfma_f32_16x16x32_bf16(af[m], bfr[n], acc[m][n], 0, 0, 0);
    }

#pragma unroll
    for (int n = 0; n < 4; n++) {
        int col = colBase + wc * 64 + n * 16 + lr;
        float bs = bias[col];
        float gm = (EPI == 3) ? gamma[col] : 0.f;
#pragma unroll
        for (int m = 0; m < 4; m++) {
            int row0 = rowBase + wr * 64 + m * 16 + lg * 4;
#pragma unroll
            for (int j = 0; j < 4; j++) {
                int row = row0 + j;
                float v = acc[m][n][j] + bs;
                if (EPI == 1) { if (col < DIM) v *= 0.125f; }
                if (EPI == 2) { v = 0.5f * v * (1.f + erff(v * 0.70710678118f)); }
                if (EPI == 3) {
                    float o = resid[(long)row * N + col] + v * gm;
                    ((float*)Cout)[(long)row * N + col] = o;
                } else {
                    ((short*)Cout)[(long)row * N + col] = f2bf(v);
                }
            }
        }
    }
}

// ---------------- Flash attention ----------------
// qkv: bf16 [TOK][3*DIM], rows = tokens (b*NN+n); Q pre-scaled by 1/8.
// out: bf16 [TOK][DIM] (head-concat layout, feeds proj GEMM directly)
__global__ __launch_bounds__(256) void attn_kernel(const short* __restrict__ qkv,
                                                   short* __restrict__ out) {
    const int qt = blockIdx.x;   // 0..31 (64 q-rows each)
    const int bh = blockIdx.y;   // 0..31
    const int b = bh >> 4, h = bh & 15;
    const int t = threadIdx.x;
    const int w = t >> 6, l = t & 63, lr = l & 15, lg = l >> 4;

    __shared__ __align__(16) short Ks[64 * 64];
    __shared__ __align__(16) short Vt[64 * 64];
    __shared__ __align__(16) short Ps[4][16 * 64];

    // Q fragments (A operand): lane holds Q[row=lr][kb*32+lg*8 .. +8]
    bf16x8 qf[2];
    {
        const int qtok = b * NN + qt * 64 + w * 16 + lr;
        const short* qp = qkv + (long)qtok * (3 * DIM) + h * HEAD_DIM;
        qf[0] = *(const bf16x8*)(qp + lg * 8);
        qf[1] = *(const bf16x8*)(qp + 32 + lg * 8);
    }

    f32x4 o[4];
#pragma unroll
    for (int dn = 0; dn < 4; dn++) o[dn] = {0.f, 0.f, 0.f, 0.f};
    float mrow[4] = {-1e30f, -1e30f, -1e30f, -1e30f};
    float lrow[4] = {0.f, 0.f, 0.f, 0.f};

    for (int kv0 = 0; kv0 < NN; kv0 += 64) {
        __syncthreads();
        // stage K tile [64 kv][64 d] linear
#pragma unroll
        for (int r = 0; r < 2; r++) {
            int c = r * 256 + t;
            int row = c >> 3, col = (c & 7) * 8;
            const short* g = qkv + (long)(b * NN + kv0 + row) * (3 * DIM) + DIM + h * HEAD_DIM + col;
            GLL16(g, Ks + (r * 256 + w * 64) * 8);
        }
        // stage V transposed: Vt[d][kv]
#pragma unroll
        for (int r = 0; r < 2; r++) {
            int c = r * 256 + t;
            int row = c >> 3, col = (c & 7) * 8;
            const short* g = qkv + (long)(b * NN + kv0 + row) * (3 * DIM) + 2 * DIM + h * HEAD_DIM + col;
            bf16x8 v = *(const bf16x8*)g;
#pragma unroll
            for (int i = 0; i < 8; i++) Vt[(col + i) * 64 + row] = v[i];
        }
        __syncthreads();

        // S = Q @ K^T  (16 q-rows x 64 kv)
        f32x4 s[4];
#pragma unroll
        for (int n = 0; n < 4; n++) s[n] = {0.f, 0.f, 0.f, 0.f};
#pragma unroll
        for (int n = 0; n < 4; n++) {
            bf16x8 kf0 = *(const bf16x8*)&Ks[(n * 16 + lr) * 64 + lg * 8];
            bf16x8 kf1 = *(const bf16x8*)&Ks[(n * 16 + lr) * 64 + 32 + lg * 8];
            s[n] = __builtin_amdgcn_mfma_f32_16x16x32_bf16(qf[0], kf0, s[n], 0, 0, 0);
            s[n] = __builtin_amdgcn_mfma_f32_16x16x32_bf16(qf[1], kf1, s[n], 0, 0, 0);
        }

        // online softmax; lane's reg j is q-row lg*4+j, col n*16+lr
#pragma unroll
        for (int j = 0; j < 4; j++) {
            float mx = fmaxf(fmaxf(s[0][j], s[1][j]), fmaxf(s[2][j], s[3][j]));
#pragma unroll
            for (int msk = 1; msk < 16; msk <<= 1) mx = fmaxf(mx, __shfl_xor(mx, msk));
            float mnew = fmaxf(mrow[j], mx);
            float corr = __expf(mrow[j] - mnew);
            float psum = 0.f;
#pragma unroll
            for (int n = 0; n < 4; n++) {
                float p = __expf(s[n][j] - mnew);
                psum += p;
                Ps[w][(lg * 4 + j) * 64 + n * 16 + lr] = f2bf(p);
            }
#pragma unroll
            for (int msk = 1; msk < 16; msk <<= 1) psum += __shfl_xor(psum, msk);
            lrow[j] = lrow[j] * corr + psum;
            mrow[j] = mnew;
#pragma unroll
            for (int dn = 0; dn < 4; dn++) o[dn][j] *= corr;
        }

        asm volatile("s_waitcnt lgkmcnt(0)" ::: "memory");

        // O += P @ V
#pragma unroll
        for (int kb = 0; kb < 2; kb++) {
            bf16x8 pf = *(const bf16x8*)&Ps[w][lr * 64 + kb * 32 + lg * 8];
#pragma unroll
            for (int dn = 0; dn < 4; dn++) {
                bf16x8 vf = *(const bf16x8*)&Vt[(dn * 16 + lr) * 64 + kb * 32 + lg * 8];
                o[dn] = __builtin_amdgcn_mfma_f32_16x16x32_bf16(pf, vf, o[dn], 0, 0, 0);
            }
        }
    }

    // epilogue
#pragma unroll
    for (int j = 0; j < 4; j++) {
        float inv = 1.f / lrow[j];
        long tok = b * NN + qt * 64 + w * 16 + lg * 4 + j;
#pragma unroll
        for (int dn = 0; dn < 4; dn++)
            out[tok * DIM + h * HEAD_DIM + dn * 16 + lr] = f2bf(o[dn][j] * inv);
    }
}

// ---------------- launch ----------------
extern "C" void kernel_launch(void* const* d_in, const int* in_sizes, int n_in,
                              void* d_out, int out_size, void* d_ws, size_t ws_size,
                              hipStream_t stream) {
    const float* x       = (const float*)d_in[0];
    const float* ln1_w   = (const float*)d_in[1];
    const float* ln1_b   = (const float*)d_in[2];
    const float* qkv_w   = (const float*)d_in[3];
    const float* qkv_b   = (const float*)d_in[4];
    const float* proj_w  = (const float*)d_in[5];
    const float* proj_b  = (const float*)d_in[6];
    const float* ls1_g   = (const float*)d_in[7];
    const float* ln2_w   = (const float*)d_in[8];
    const float* ln2_b   = (const float*)d_in[9];
    const float* fc1_w   = (const float*)d_in[10];
    const float* fc1_b   = (const float*)d_in[11];
    const float* fc2_w   = (const float*)d_in[12];
    const float* fc2_b   = (const float*)d_in[13];
    const float* ls2_g   = (const float*)d_in[14];

    char* p = (char*)d_ws;
    short* wqkv   = (short*)p; p += (size_t)3 * DIM * DIM * 2;        // 6 MB
    short* wproj  = (short*)p; p += (size_t)DIM * DIM * 2;            // 2 MB
    short* wfc1   = (short*)p; p += (size_t)HIDDEN * DIM * 2;         // 8 MB
    short* wfc2   = (short*)p; p += (size_t)DIM * HIDDEN * 2;         // 8 MB
    short* h1     = (short*)p; p += (size_t)TOK * DIM * 2;            // 8 MB
    short* qkvbuf = (short*)p; p += (size_t)TOK * 3 * DIM * 2;        // 24 MB
    short* attno  = (short*)p; p += (size_t)TOK * DIM * 2;            // 8 MB
    float* x2     = (float*)p; p += (size_t)TOK * DIM * 4;            // 16 MB
    short* h2     = (short*)p; p += (size_t)TOK * DIM * 2;            // 8 MB
    short* fc1o   = (short*)p; p += (size_t)TOK * HIDDEN * 2;         // 32 MB

    // weight conversion
    {
        int n4;
        n4 = 3 * DIM * DIM / 4;
        cvt_kernel<<<dim3(2048), dim3(256), 0, stream>>>(qkv_w, wqkv, n4);
        n4 = DIM * DIM / 4;
        cvt_kernel<<<dim3(1024), dim3(256), 0, stream>>>(proj_w, wproj, n4);
        n4 = HIDDEN * DIM / 4;
        cvt_kernel<<<dim3(2048), dim3(256), 0, stream>>>(fc1_w, wfc1, n4);
        n4 = DIM * HIDDEN / 4;
        cvt_kernel<<<dim3(2048), dim3(256), 0, stream>>>(fc2_w, wfc2, n4);
    }

    // LN1
    ln_kernel<<<dim3(TOK), dim3(256), 0, stream>>>(x, ln1_w, ln1_b, h1);

    // QKV = h1 @ qkv_w^T + qkv_b  (Q scaled by 0.125)
    gemm_bt<1><<<dim3(3 * DIM / 128, TOK / 128), dim3(256), 0, stream>>>(
        h1, wqkv, qkv_b, nullptr, nullptr, qkvbuf, TOK, 3 * DIM, DIM);

    // attention
    attn_kernel<<<dim3(NN / 64, BB * HEADS), dim3(256), 0, stream>>>(qkvbuf, attno);

    // proj + residual + layer-scale -> x2 (fp32)
    gemm_bt<3><<<dim3(DIM / 128, TOK / 128), dim3(256), 0, stream>>>(
        attno, wproj, proj_b, x, ls1_g, x2, TOK, DIM, DIM);

    // LN2
    ln_kernel<<<dim3(TOK), dim3(256), 0, stream>>>(x2, ln2_w, ln2_b, h2);

    // FC1 + GELU
    gemm_bt<2><<<dim3(HIDDEN / 128, TOK / 128), dim3(256), 0, stream>>>(
        h2, wfc1, fc1_b, nullptr, nullptr, fc1o, TOK, HIDDEN, DIM);

    // FC2 + residual + layer-scale -> d_out (fp32)
    gemm_bt<3><<<dim3(DIM / 128, TOK / 128), dim3(256), 0, stream>>>(
        fc1o, wfc2, fc2_b, x2, ls2_g, (float*)d_out, TOK, DIM, HIDDEN);
}

// Round 2
// 473.851 us; speedup vs baseline: 1.1691x; 1.1691x over previous
//
#include <hip/hip_runtime.h>

#define DIM 1024
#define HEADS 16
#define HEAD_DIM 64
#define HIDDEN 4096
#define BB 2
#define NN 2048
#define TOK (BB*NN)          // 4096 rows

typedef __attribute__((ext_vector_type(8))) short bf16x8;
typedef __attribute__((ext_vector_type(4))) float f32x4;
typedef __attribute__((ext_vector_type(2))) int i32x2;

__device__ inline short f2bf(float f) {
    unsigned u = __float_as_uint(f);
    unsigned r = (u + 0x7fff + ((u >> 16) & 1)) >> 16;
    return (short)r;
}

#define GLL16(g, l)                                                          \
    __builtin_amdgcn_global_load_lds(                                        \
        (const __attribute__((address_space(1))) void*)(g),                  \
        (__attribute__((address_space(3))) void*)(l), 16, 0, 0)

// ---------------- fp32 -> bf16 convert ----------------
__global__ void cvt_kernel(const float* __restrict__ in, short* __restrict__ out, int n4) {
    int i = blockIdx.x * blockDim.x + threadIdx.x;
    int stride = gridDim.x * blockDim.x;
    for (; i < n4; i += stride) {
        float4 v = ((const float4*)in)[i];
        short4 o;
        o.x = f2bf(v.x); o.y = f2bf(v.y); o.z = f2bf(v.z); o.w = f2bf(v.w);
        ((short4*)out)[i] = o;
    }
}

// ---------------- LayerNorm (per-row, DIM=1024) -> bf16 ----------------
__global__ __launch_bounds__(256) void ln_kernel(const float* __restrict__ x,
                                                 const float* __restrict__ w,
                                                 const float* __restrict__ b,
                                                 short* __restrict__ out) {
    const int row = blockIdx.x;
    const int t = threadIdx.x;
    float4 v = ((const float4*)(x + (long)row * DIM))[t];
    float s = v.x + v.y + v.z + v.w;
    float ss = v.x * v.x + v.y * v.y + v.z * v.z + v.w * v.w;
#pragma unroll
    for (int m = 1; m < 64; m <<= 1) {
        s += __shfl_xor(s, m);
        ss += __shfl_xor(ss, m);
    }
    __shared__ float rs[4], rss[4];
    int wv = t >> 6;
    if ((t & 63) == 0) { rs[wv] = s; rss[wv] = ss; }
    __syncthreads();
    s = rs[0] + rs[1] + rs[2] + rs[3];
    ss = rss[0] + rss[1] + rss[2] + rss[3];
    float mean = s * (1.f / DIM);
    float var = ss * (1.f / DIM) - mean * mean;
    float rstd = rsqrtf(var + 1e-5f);
    float4 wv4 = ((const float4*)w)[t];
    float4 bv4 = ((const float4*)b)[t];
    short4 o;
    o.x = f2bf((v.x - mean) * rstd * wv4.x + bv4.x);
    o.y = f2bf((v.y - mean) * rstd * wv4.y + bv4.y);
    o.z = f2bf((v.z - mean) * rstd * wv4.z + bv4.z);
    o.w = f2bf((v.w - mean) * rstd * wv4.w + bv4.w);
    ((short4*)(out + (long)row * DIM))[t] = o;
}

// ---------------- GEMM: C[M,N] = A[M,K] @ Bt[N,K]^T + bias ----------------
// EPI: 0 plain bf16 out; 1 qkv (scale cols<DIM by 0.125, bf16 out);
//      2 gelu bf16 out; 3 residual+layer-scale fp32 out
template <int EPI>
__global__ __launch_bounds__(256) void gemm_bt(const short* __restrict__ A,
                                               const short* __restrict__ Bt,
                                               const float* __restrict__ bias,
                                               const float* __restrict__ resid,
                                               const float* __restrict__ gamma,
                                               void* __restrict__ Cout,
                                               int M, int N, int K) {
    __shared__ __align__(16) short As[128 * 32];
    __shared__ __align__(16) short Bs[128 * 32];
    const int t = threadIdx.x;
    const int w = t >> 6, l = t & 63, lr = l & 15, lg = l >> 4;
    const int wr = w >> 1, wc = w & 1;
    const int rowBase = blockIdx.y * 128, colBase = blockIdx.x * 128;

    f32x4 acc[4][4];
#pragma unroll
    for (int m = 0; m < 4; m++)
#pragma unroll
        for (int n = 0; n < 4; n++) acc[m][n] = {0.f, 0.f, 0.f, 0.f};

    for (int k0 = 0; k0 < K; k0 += 32) {
        __syncthreads();
#pragma unroll
        for (int r = 0; r < 2; r++) {
            int c = r * 256 + t;
            int row = c >> 2, col = (c & 3) * 8;
            const short* ga = A + (long)(rowBase + row) * K + k0 + col;
            const short* gb = Bt + (long)(colBase + row) * K + k0 + col;
            int ldsoff = (r * 256 + w * 64) * 8;
            GLL16(ga, As + ldsoff);
            GLL16(gb, Bs + ldsoff);
        }
        __syncthreads();
        bf16x8 af[4], bfr[4];
#pragma unroll
        for (int m = 0; m < 4; m++)
            af[m] = *(const bf16x8*)&As[(wr * 64 + m * 16 + lr) * 32 + lg * 8];
#pragma unroll
        for (int n = 0; n < 4; n++)
            bfr[n] = *(const bf16x8*)&Bs[(wc * 64 + n * 16 + lr) * 32 + lg * 8];
#pragma unroll
        for (int m = 0; m < 4; m++)
#pragma unroll
            for (int n = 0; n < 4; n++)
                acc[m][n] = __builtin_amdgcn_mfma_f32_16x16x32_bf16(af[m], bfr[n], acc[m][n], 0, 0, 0);
    }

#pragma unroll
    for (int n = 0; n < 4; n++) {
        int col = colBase + wc * 64 + n * 16 + lr;
        float bs = bias[col];
        float gm = (EPI == 3) ? gamma[col] : 0.f;
#pragma unroll
        for (int m = 0; m < 4; m++) {
            int row0 = rowBase + wr * 64 + m * 16 + lg * 4;
#pragma unroll
            for (int j = 0; j < 4; j++) {
                int row = row0 + j;
                float v = acc[m][n][j] + bs;
                if (EPI == 1) { if (col < DIM) v *= 0.125f; }
                if (EPI == 2) { v = 0.5f * v * (1.f + erff(v * 0.70710678118f)); }
                if (EPI == 3) {
                    float o = resid[(long)row * N + col] + v * gm;
                    ((float*)Cout)[(long)row * N + col] = o;
                } else {
                    ((short*)Cout)[(long)row * N + col] = f2bf(v);
                }
            }
        }
    }
}

// ---------------- Flash attention (v2: swizzled K/P, tr-read V, dbuf) ------
// qkv: bf16 [TOK][3*DIM]; Q pre-scaled by 1/8.
// out: bf16 [TOK][DIM]
// K tile LDS: [64 kv][64 d], 16B slots XOR-swizzled by ((row&7)<<4) bytes,
//   staged linearly via global_load_lds with pre-swizzled global source.
// V tile LDS: 4x16-subtiled: ofs(kv,d) = (kv>>2)*256 + (d>>4)*64 + (kv&3)*16 + (d&15),
//   staged linearly via per-lane source remap; consumed with ds_read_b64_tr_b16.
// P tile LDS: per-wave [16][64], shorts XOR-swizzled by ((row&7)<<3).
__global__ __launch_bounds__(256) void attn_kernel(const short* __restrict__ qkv,
                                                   short* __restrict__ out) {
    // XCD-contiguous remap: 1024 blocks -> 8 XCDs x 128; bh-major within XCD
    const int id = blockIdx.x;
    const int rank = (id & 7) * 128 + (id >> 3);
    const int bh = rank >> 5, qt = rank & 31;
    const int b = bh >> 4, h = bh & 15;
    const int t = threadIdx.x;
    const int w = t >> 6, l = t & 63, lr = l & 15, lg = l >> 4;

    __shared__ __align__(16) short Ks[2][4096];
    __shared__ __align__(16) short Vs[2][4096];
    __shared__ __align__(16) short Ps[4][1024];

    // Q fragments (A operand): lane holds Q[row=lr][kb*32+lg*8 .. +8]
    bf16x8 qf[2];
    {
        const int qtok = b * NN + qt * 64 + w * 16 + lr;
        const short* qp = qkv + (long)qtok * (3 * DIM) + h * HEAD_DIM;
        qf[0] = *(const bf16x8*)(qp + lg * 8);
        qf[1] = *(const bf16x8*)(qp + 32 + lg * 8);
    }

    bf16x8 ones;
#pragma unroll
    for (int i = 0; i < 8; i++) ones[i] = (short)0x3F80;  // bf16 1.0

    f32x4 o[4];
#pragma unroll
    for (int dn = 0; dn < 4; dn++) o[dn] = {0.f, 0.f, 0.f, 0.f};
    float mrow[4] = {-1e30f, -1e30f, -1e30f, -1e30f};
    float lrow[4] = {0.f, 0.f, 0.f, 0.f};

    const long tokbase = (long)(b * NN) * (3 * DIM);

    // stage K (swizzled) + V (subtiled) for tile at kv0 into buffer cb
    auto stage = [&](int cb, int kv0) {
#pragma unroll
        for (int r = 0; r < 2; r++) {
            int L = r * 256 + t;
            // K: dest chunk L -> row=L>>3, 16B slot L&7; source col pre-swizzled
            int krow = L >> 3;
            int kcol = ((L & 7) * 8) ^ ((krow & 7) << 3);   // shorts
            const short* gk = qkv + tokbase + (long)(kv0 + krow) * (3 * DIM) + DIM + h * HEAD_DIM + kcol;
            GLL16(gk, &Ks[cb][(r * 256 + w * 64) * 8]);
            // V: dest chunk L -> (kv, d) per subtile inverse map
            int kv = ((L >> 5) << 2) | ((L >> 1) & 3);
            int d  = ((L >> 3) & 3) * 16 + (L & 1) * 8;
            const short* gv = qkv + tokbase + (long)(kv0 + kv) * (3 * DIM) + 2 * DIM + h * HEAD_DIM + d;
            GLL16(gv, &Vs[cb][(r * 256 + w * 64) * 8]);
        }
    };

    stage(0, 0);
    int cur = 0;

    for (int kvt = 0; kvt < NN / 64; kvt++) {
        __syncthreads();                    // drains vmcnt -> buf[cur] ready
        if (kvt + 1 < NN / 64) stage(cur ^ 1, (kvt + 1) * 64);

        // ---- S = Q @ K^T (16 q-rows x 64 kv) ----
        const int kswz = (lr & 7) << 3;
        f32x4 s[4];
#pragma unroll
        for (int n = 0; n < 4; n++) {
            int rowoff = (n * 16 + lr) * 64;
            bf16x8 kf0 = *(const bf16x8*)&Ks[cur][rowoff + ((lg * 8) ^ kswz)];
            bf16x8 kf1 = *(const bf16x8*)&Ks[cur][rowoff + ((32 + lg * 8) ^ kswz)];
            s[n] = {0.f, 0.f, 0.f, 0.f};
            s[n] = __builtin_amdgcn_mfma_f32_16x16x32_bf16(qf[0], kf0, s[n], 0, 0, 0);
            s[n] = __builtin_amdgcn_mfma_f32_16x16x32_bf16(qf[1], kf1, s[n], 0, 0, 0);
        }

        // ---- online softmax: row max via 16-lane shuffle; P -> LDS (swizzled) ----
        float corr[4];
#pragma unroll
        for (int j = 0; j < 4; j++) {
            float mx = fmaxf(fmaxf(s[0][j], s[1][j]), fmaxf(s[2][j], s[3][j]));
#pragma unroll
            for (int msk = 1; msk < 16; msk <<= 1) mx = fmaxf(mx, __shfl_xor(mx, msk));
            float mnew = fmaxf(mrow[j], mx);
            corr[j] = __expf(mrow[j] - mnew);
            mrow[j] = mnew;
            int prow = lg * 4 + j;
            int pswz = (prow & 7) << 3;
#pragma unroll
            for (int n = 0; n < 4; n++) {
                float p = __expf(s[n][j] - mnew);
                Ps[w][prow * 64 + ((n * 16 + lr) ^ pswz)] = f2bf(p);
            }
#pragma unroll
            for (int dn = 0; dn < 4; dn++) o[dn][j] *= corr[j];
        }

        // ---- V fragments via hardware transpose read (issue all, wait once) ----
        i32x2 vrlo[2][4], vrhi[2][4];
#pragma unroll
        for (int kb = 0; kb < 2; kb++)
#pragma unroll
            for (int dn = 0; dn < 4; dn++) {
                unsigned voff = (unsigned)(size_t)&Vs[cur][(kb * 8 + lg * 2) * 256 + dn * 64 + lr];
                asm volatile("ds_read_b64_tr_b16 %0, %2\n\t"
                             "ds_read_b64_tr_b16 %1, %2 offset:512"
                             : "=&v"(vrlo[kb][dn]), "=&v"(vrhi[kb][dn])
                             : "v"(voff));
            }
        asm volatile("s_waitcnt lgkmcnt(0)" ::: "memory");
        __builtin_amdgcn_sched_barrier(0);

        // ---- O += P @ V ; row-sums via MFMA with ones ----
        f32x4 lsum = {0.f, 0.f, 0.f, 0.f};
#pragma unroll
        for (int kb = 0; kb < 2; kb++) {
            bf16x8 pf = *(const bf16x8*)&Ps[w][lr * 64 + ((kb * 32 + lg * 8) ^ ((lr & 7) << 3))];
            lsum = __builtin_amdgcn_mfma_f32_16x16x32_bf16(pf, ones, lsum, 0, 0, 0);
#pragma unroll
            for (int dn = 0; dn < 4; dn++) {
                union { i32x2 p[2]; bf16x8 v; } u;
                u.p[0] = vrlo[kb][dn];
                u.p[1] = vrhi[kb][dn];
                o[dn] = __builtin_amdgcn_mfma_f32_16x16x32_bf16(pf, u.v, o[dn], 0, 0, 0);
            }
        }
#pragma unroll
        for (int j = 0; j < 4; j++) lrow[j] = lrow[j] * corr[j] + lsum[j];

        cur ^= 1;
    }

    // epilogue
#pragma unroll
    for (int j = 0; j < 4; j++) {
        float inv = 1.f / lrow[j];
        long tok = b * NN + qt * 64 + w * 16 + lg * 4 + j;
#pragma unroll
        for (int dn = 0; dn < 4; dn++)
            out[tok * DIM + h * HEAD_DIM + dn * 16 + lr] = f2bf(o[dn][j] * inv);
    }
}

// ---------------- launch ----------------
extern "C" void kernel_launch(void* const* d_in, const int* in_sizes, int n_in,
                              void* d_out, int out_size, void* d_ws, size_t ws_size,
                              hipStream_t stream) {
    const float* x       = (const float*)d_in[0];
    const float* ln1_w   = (const float*)d_in[1];
    const float* ln1_b   = (const float*)d_in[2];
    const float* qkv_w   = (const float*)d_in[3];
    const float* qkv_b   = (const float*)d_in[4];
    const float* proj_w  = (const float*)d_in[5];
    const float* proj_b  = (const float*)d_in[6];
    const float* ls1_g   = (const float*)d_in[7];
    const float* ln2_w   = (const float*)d_in[8];
    const float* ln2_b   = (const float*)d_in[9];
    const float* fc1_w   = (const float*)d_in[10];
    const float* fc1_b   = (const float*)d_in[11];
    const float* fc2_w   = (const float*)d_in[12];
    const float* fc2_b   = (const float*)d_in[13];
    const float* ls2_g   = (const float*)d_in[14];

    char* p = (char*)d_ws;
    short* wqkv   = (short*)p; p += (size_t)3 * DIM * DIM * 2;
    short* wproj  = (short*)p; p += (size_t)DIM * DIM * 2;
    short* wfc1   = (short*)p; p += (size_t)HIDDEN * DIM * 2;
    short* wfc2   = (short*)p; p += (size_t)DIM * HIDDEN * 2;
    short* h1     = (short*)p; p += (size_t)TOK * DIM * 2;
    short* qkvbuf = (short*)p; p += (size_t)TOK * 3 * DIM * 2;
    short* attno  = (short*)p; p += (size_t)TOK * DIM * 2;
    float* x2     = (float*)p; p += (size_t)TOK * DIM * 4;
    short* h2     = (short*)p; p += (size_t)TOK * DIM * 2;
    short* fc1o   = (short*)p; p += (size_t)TOK * HIDDEN * 2;

    // weight conversion
    {
        int n4;
        n4 = 3 * DIM * DIM / 4;
        cvt_kernel<<<dim3(2048), dim3(256), 0, stream>>>(qkv_w, wqkv, n4);
        n4 = DIM * DIM / 4;
        cvt_kernel<<<dim3(1024), dim3(256), 0, stream>>>(proj_w, wproj, n4);
        n4 = HIDDEN * DIM / 4;
        cvt_kernel<<<dim3(2048), dim3(256), 0, stream>>>(fc1_w, wfc1, n4);
        n4 = DIM * HIDDEN / 4;
        cvt_kernel<<<dim3(2048), dim3(256), 0, stream>>>(fc2_w, wfc2, n4);
    }

    // LN1
    ln_kernel<<<dim3(TOK), dim3(256), 0, stream>>>(x, ln1_w, ln1_b, h1);

    // QKV = h1 @ qkv_w^T + qkv_b  (Q scaled by 0.125)
    gemm_bt<1><<<dim3(3 * DIM / 128, TOK / 128), dim3(256), 0, stream>>>(
        h1, wqkv, qkv_b, nullptr, nullptr, qkvbuf, TOK, 3 * DIM, DIM);

    // attention
    attn_kernel<<<dim3(NN / 64 * BB * HEADS), dim3(256), 0, stream>>>(qkvbuf, attno);

    // proj + residual + layer-scale -> x2 (fp32)
    gemm_bt<3><<<dim3(DIM / 128, TOK / 128), dim3(256), 0, stream>>>(
        attno, wproj, proj_b, x, ls1_g, x2, TOK, DIM, DIM);

    // LN2
    ln_kernel<<<dim3(TOK), dim3(256), 0, stream>>>(x2, ln2_w, ln2_b, h2);

    // FC1 + GELU
    gemm_bt<2><<<dim3(HIDDEN / 128, TOK / 128), dim3(256), 0, stream>>>(
        h2, wfc1, fc1_b, nullptr, nullptr, fc1o, TOK, HIDDEN, DIM);

    // FC2 + residual + layer-scale -> d_out (fp32)
    gemm_bt<3><<<dim3(DIM / 128, TOK / 128), dim3(256), 0, stream>>>(
        fc1o, wfc2, fc2_b, x2, ls2_g, (float*)d_out, TOK, DIM, HIDDEN);
}

// Round 5
// 468.495 us; speedup vs baseline: 1.1825x; 1.0114x over previous
//
#include <hip/hip_runtime.h>

#define DIM 1024
#define HEADS 16
#define HEAD_DIM 64
#define HIDDEN 4096
#define BB 2
#define NN 2048
#define TOK (BB*NN)          // 4096 rows

typedef __attribute__((ext_vector_type(8))) short bf16x8;
typedef __attribute__((ext_vector_type(4))) float f32x4;
typedef __attribute__((ext_vector_type(2))) int i32x2;

__device__ inline short f2bf(float f) {
    unsigned u = __float_as_uint(f);
    unsigned r = (u + 0x7fff + ((u >> 16) & 1)) >> 16;
    return (short)r;
}

#define GLL16(g, l)                                                          \
    __builtin_amdgcn_global_load_lds(                                        \
        (const __attribute__((address_space(1))) void*)(g),                  \
        (__attribute__((address_space(3))) void*)(l), 16, 0, 0)

#define BARRIER() do { asm volatile("" ::: "memory");                        \
    __builtin_amdgcn_s_barrier();                                            \
    asm volatile("" ::: "memory"); } while (0)

// ---------------- fp32 -> bf16 convert ----------------
__global__ void cvt_kernel(const float* __restrict__ in, short* __restrict__ out, int n4) {
    int i = blockIdx.x * blockDim.x + threadIdx.x;
    int stride = gridDim.x * blockDim.x;
    for (; i < n4; i += stride) {
        float4 v = ((const float4*)in)[i];
        short4 o;
        o.x = f2bf(v.x); o.y = f2bf(v.y); o.z = f2bf(v.z); o.w = f2bf(v.w);
        ((short4*)out)[i] = o;
    }
}

// ---------------- LayerNorm (per-row, DIM=1024) -> bf16 ----------------
__global__ __launch_bounds__(256) void ln_kernel(const float* __restrict__ x,
                                                 const float* __restrict__ w,
                                                 const float* __restrict__ b,
                                                 short* __restrict__ out) {
    const int row = blockIdx.x;
    const int t = threadIdx.x;
    float4 v = ((const float4*)(x + (long)row * DIM))[t];
    float s = v.x + v.y + v.z + v.w;
    float ss = v.x * v.x + v.y * v.y + v.z * v.z + v.w * v.w;
#pragma unroll
    for (int m = 1; m < 64; m <<= 1) {
        s += __shfl_xor(s, m);
        ss += __shfl_xor(ss, m);
    }
    __shared__ float rs[4], rss[4];
    int wv = t >> 6;
    if ((t & 63) == 0) { rs[wv] = s; rss[wv] = ss; }
    __syncthreads();
    s = rs[0] + rs[1] + rs[2] + rs[3];
    ss = rss[0] + rss[1] + rss[2] + rss[3];
    float mean = s * (1.f / DIM);
    float var = ss * (1.f / DIM) - mean * mean;
    float rstd = rsqrtf(var + 1e-5f);
    float4 wv4 = ((const float4*)w)[t];
    float4 bv4 = ((const float4*)b)[t];
    short4 o;
    o.x = f2bf((v.x - mean) * rstd * wv4.x + bv4.x);
    o.y = f2bf((v.y - mean) * rstd * wv4.y + bv4.y);
    o.z = f2bf((v.z - mean) * rstd * wv4.z + bv4.z);
    o.w = f2bf((v.w - mean) * rstd * wv4.w + bv4.w);
    ((short4*)(out + (long)row * DIM))[t] = o;
}

// ================= 256x256 8-phase GEMM (T1+T2+T3+T4+T5) ==================
// C[M,N] = A[M,K] @ Bt[N,K]^T + bias, bf16 in/out.
// EPI: 1 qkv (scale cols<DIM by 0.125); 2 gelu.
// 8 waves (2Mx4N), per-wave 128x64 out = acc[8][4]. BK=64, dbuf, K%128==0.
// LDS halves are WAVE-MAJOR splits so each half's last read is 2 phases
// before its restage (race-free with per-phase barriers):
//   A half h, phys p in [0,128): global row = (p>>6)*128 + h*64 + (p&63)
//   B half h, phys p:            global row = (p>>5)*64  + h*32 + (p&31)
// Swizzle (T2): byte ^= (physrow&7)<<4, applied on read; staging keeps dest
// linear and pre-swizzles the GLOBAL source column (rule #21).
template <int EPI>
__global__ __launch_bounds__(512, 2) void gemm8(const short* __restrict__ A,
                                                const short* __restrict__ Bt,
                                                const float* __restrict__ bias,
                                                short* __restrict__ Cout,
                                                int M, int N, int K, int nbx) {
    __shared__ __align__(16) short As[2][2][128 * 64];
    __shared__ __align__(16) short Bs[2][2][128 * 64];

    const int t = threadIdx.x;
    const int w = t >> 6, l = t & 63, lr = l & 15, lg = l >> 4;
    const int wr = w >> 2, wc = w & 3;

    // T1: bijective XCD swizzle (grid %8 == 0 for both users)
    const int nwg = gridDim.x;
    const int id = blockIdx.x;
    const int r = (id & 7) * (nwg >> 3) + (id >> 3);
    const int by = r / nbx, bx = r % nbx;
    const int rowBase = by * 256, colBase = bx * 256;

    f32x4 acc[8][4];
#pragma unroll
    for (int m = 0; m < 8; m++)
#pragma unroll
        for (int n = 0; n < 4; n++) acc[m][n] = {0.f, 0.f, 0.f, 0.f};

    bf16x8 afr[4][2];   // current m-half A fragments
    bf16x8 bfr[4][2];   // both n-halves' B fragments

    const int NT = K >> 6;          // K-tiles of 64
    const int ITERS = NT >> 1;      // 2 K-tiles per iteration

    auto stageA = [&](int buf, int h, int tile) {
        const long k0 = (long)tile * 64;
#pragma unroll
        for (int j = 0; j < 2; j++) {
            int L = j * 512 + t;
            int p = L >> 3;
            int grow = ((p >> 6) << 7) + (h << 6) + (p & 63);
            int colS = ((L & 7) ^ (p & 7)) << 3;
            const short* g = A + (long)(rowBase + grow) * K + k0 + colS;
            GLL16(g, &As[buf][h][(j * 512 + w * 64) * 8]);
        }
    };
    auto stageB = [&](int buf, int h, int tile) {
        const long k0 = (long)tile * 64;
#pragma unroll
        for (int j = 0; j < 2; j++) {
            int L = j * 512 + t;
            int p = L >> 3;
            int grow = ((p >> 5) << 6) + (h << 5) + (p & 31);
            int colS = ((L & 7) ^ (p & 7)) << 3;
            const short* g = Bt + (long)(colBase + grow) * K + k0 + colS;
            GLL16(g, &Bs[buf][h][(j * 512 + w * 64) * 8]);
        }
    };
    auto ldA = [&](int buf, int mh) {
#pragma unroll
        for (int mm = 0; mm < 4; mm++) {
            int phys = wr * 64 + mm * 16 + lr;
            int base = phys * 64, sw = (phys & 7) << 3;
#pragma unroll
            for (int ks = 0; ks < 2; ks++)
                afr[mm][ks] = *(const bf16x8*)&As[buf][mh][base + ((ks * 32 + lg * 8) ^ sw)];
        }
    };
    auto ldB = [&](int buf, int nh) {
#pragma unroll
        for (int nn = 0; nn < 2; nn++) {
            int phys = wc * 32 + nn * 16 + lr;
            int base = phys * 64, sw = (phys & 7) << 3;
#pragma unroll
            for (int ks = 0; ks < 2; ks++)
                bfr[nh * 2 + nn][ks] = *(const bf16x8*)&Bs[buf][nh][base + ((ks * 32 + lg * 8) ^ sw)];
        }
    };
    auto mfma16 = [&](int mh, int nh) {
        __builtin_amdgcn_s_setprio(1);
#pragma unroll
        for (int ks = 0; ks < 2; ks++)
#pragma unroll
            for (int mm = 0; mm < 4; mm++)
#pragma unroll
                for (int nn = 0; nn < 2; nn++)
                    acc[mh * 4 + mm][nh * 2 + nn] = __builtin_amdgcn_mfma_f32_16x16x32_bf16(
                        afr[mm][ks], bfr[nh * 2 + nn][ks], acc[mh * 4 + mm][nh * 2 + nn], 0, 0, 0);
        __builtin_amdgcn_s_setprio(0);
    };

    // prologue: tile0 full into buf0, tile1's h0 halves into buf1
    stageA(0, 0, 0); stageB(0, 0, 0);
    stageA(0, 1, 0); stageB(0, 1, 0);
    stageA(1, 0, 1); stageB(1, 0, 1);
    asm volatile("s_waitcnt vmcnt(4)" ::: "memory");   // tile0 landed
    BARRIER();

    for (int i = 0; i < ITERS; i++) {
        const bool more = (i < ITERS - 1);
        // ph1: (m0,n0) of tile 2i (buf0)
        ldA(0, 0); ldB(0, 0);
        stageA(1, 1, 2 * i + 1);
        BARRIER(); mfma16(0, 0); BARRIER();
        // ph2: (m0,n1)
        ldB(0, 1);
        stageB(1, 1, 2 * i + 1);
        BARRIER(); mfma16(0, 1); BARRIER();
        // ph3: (m1,n0)
        ldA(0, 1);
        if (more) stageA(0, 0, 2 * i + 2);
        BARRIER(); mfma16(1, 0); BARRIER();
        // ph4: (m1,n1)  [counted vmcnt]
        if (more) { stageB(0, 0, 2 * i + 2);
                    asm volatile("s_waitcnt vmcnt(4)" ::: "memory"); }
        else      { asm volatile("s_waitcnt vmcnt(0)" ::: "memory"); }
        BARRIER(); mfma16(1, 1); BARRIER();
        // ph5: (m0,n0) of tile 2i+1 (buf1)
        ldA(1, 0); ldB(1, 0);
        if (more) stageA(0, 1, 2 * i + 2);
        BARRIER(); mfma16(0, 0); BARRIER();
        // ph6: (m0,n1)
        ldB(1, 1);
        if (more) stageB(0, 1, 2 * i + 2);
        BARRIER(); mfma16(0, 1); BARRIER();
        // ph7: (m1,n0)
        ldA(1, 1);
        if (more) stageA(1, 0, 2 * i + 3);
        BARRIER(); mfma16(1, 0); BARRIER();
        // ph8: (m1,n1)  [counted vmcnt]
        if (more) { stageB(1, 0, 2 * i + 3);
                    asm volatile("s_waitcnt vmcnt(4)" ::: "memory"); }
        else      { asm volatile("s_waitcnt vmcnt(0)" ::: "memory"); }
        BARRIER(); mfma16(1, 1); BARRIER();
    }

    // epilogue
#pragma unroll
    for (int n = 0; n < 4; n++) {
        int col = colBase + wc * 64 + n * 16 + lr;
        float bs = bias[col];
#pragma unroll
        for (int m = 0; m < 8; m++) {
            int row0 = rowBase + wr * 128 + m * 16 + lg * 4;
#pragma unroll
            for (int j = 0; j < 4; j++) {
                float v = acc[m][n][j] + bs;
                if (EPI == 1) { if (col < DIM) v *= 0.125f; }
                if (EPI == 2) { v = 0.5f * v * (1.f + erff(v * 0.70710678118f)); }
                Cout[(long)(row0 + j) * N + col] = f2bf(v);
            }
        }
    }
}

// ---------------- 128x128 GEMM (kept for N=1024 shapes) -------------------
// EPI 3: residual + layer-scale, fp32 out
template <int EPI>
__global__ __launch_bounds__(256) void gemm_bt(const short* __restrict__ A,
                                               const short* __restrict__ Bt,
                                               const float* __restrict__ bias,
                                               const float* __restrict__ resid,
                                               const float* __restrict__ gamma,
                                               void* __restrict__ Cout,
                                               int M, int N, int K) {
    __shared__ __align__(16) short As[128 * 32];
    __shared__ __align__(16) short Bs[128 * 32];
    const int t = threadIdx.x;
    const int w = t >> 6, l = t & 63, lr = l & 15, lg = l >> 4;
    const int wr = w >> 1, wc = w & 1;
    const int rowBase = blockIdx.y * 128, colBase = blockIdx.x * 128;

    f32x4 acc[4][4];
#pragma unroll
    for (int m = 0; m < 4; m++)
#pragma unroll
        for (int n = 0; n < 4; n++) acc[m][n] = {0.f, 0.f, 0.f, 0.f};

    for (int k0 = 0; k0 < K; k0 += 32) {
        __syncthreads();
#pragma unroll
        for (int r = 0; r < 2; r++) {
            int c = r * 256 + t;
            int row = c >> 2, col = (c & 3) * 8;
            const short* ga = A + (long)(rowBase + row) * K + k0 + col;
            const short* gb = Bt + (long)(colBase + row) * K + k0 + col;
            int ldsoff = (r * 256 + w * 64) * 8;
            GLL16(ga, As + ldsoff);
            GLL16(gb, Bs + ldsoff);
        }
        __syncthreads();
        bf16x8 af[4], bfr[4];
#pragma unroll
        for (int m = 0; m < 4; m++)
            af[m] = *(const bf16x8*)&As[(wr * 64 + m * 16 + lr) * 32 + lg * 8];
#pragma unroll
        for (int n = 0; n < 4; n++)
            bfr[n] = *(const bf16x8*)&Bs[(wc * 64 + n * 16 + lr) * 32 + lg * 8];
#pragma unroll
        for (int m = 0; m < 4; m++)
#pragma unroll
            for (int n = 0; n < 4; n++)
                acc[m][n] = __builtin_amdgcn_mfma_f32_16x16x32_bf16(af[m], bfr[n], acc[m][n], 0, 0, 0);
    }

#pragma unroll
    for (int n = 0; n < 4; n++) {
        int col = colBase + wc * 64 + n * 16 + lr;
        float bs = bias[col];
        float gm = (EPI == 3) ? gamma[col] : 0.f;
#pragma unroll
        for (int m = 0; m < 4; m++) {
            int row0 = rowBase + wr * 64 + m * 16 + lg * 4;
#pragma unroll
            for (int j = 0; j < 4; j++) {
                int row = row0 + j;
                float v = acc[m][n][j] + bs;
                if (EPI == 3) {
                    float o = resid[(long)row * N + col] + v * gm;
                    ((float*)Cout)[(long)row * N + col] = o;
                } else {
                    ((short*)Cout)[(long)row * N + col] = f2bf(v);
                }
            }
        }
    }
}

// ---------------- Flash attention (swizzled K/P, tr-read V, dbuf) ---------
__global__ __launch_bounds__(256) void attn_kernel(const short* __restrict__ qkv,
                                                   short* __restrict__ out) {
    const int id = blockIdx.x;
    const int rank = (id & 7) * 128 + (id >> 3);
    const int bh = rank >> 5, qt = rank & 31;
    const int b = bh >> 4, h = bh & 15;
    const int t = threadIdx.x;
    const int w = t >> 6, l = t & 63, lr = l & 15, lg = l >> 4;

    __shared__ __align__(16) short Ks[2][4096];
    __shared__ __align__(16) short Vs[2][4096];
    __shared__ __align__(16) short Ps[4][1024];

    bf16x8 qf[2];
    {
        const int qtok = b * NN + qt * 64 + w * 16 + lr;
        const short* qp = qkv + (long)qtok * (3 * DIM) + h * HEAD_DIM;
        qf[0] = *(const bf16x8*)(qp + lg * 8);
        qf[1] = *(const bf16x8*)(qp + 32 + lg * 8);
    }

    bf16x8 ones;
#pragma unroll
    for (int i = 0; i < 8; i++) ones[i] = (short)0x3F80;

    f32x4 o[4];
#pragma unroll
    for (int dn = 0; dn < 4; dn++) o[dn] = {0.f, 0.f, 0.f, 0.f};
    float mrow[4] = {-1e30f, -1e30f, -1e30f, -1e30f};
    float lrow[4] = {0.f, 0.f, 0.f, 0.f};

    const long tokbase = (long)(b * NN) * (3 * DIM);

    auto stage = [&](int cb, int kv0) {
#pragma unroll
        for (int r = 0; r < 2; r++) {
            int L = r * 256 + t;
            int krow = L >> 3;
            int kcol = ((L & 7) * 8) ^ ((krow & 7) << 3);
            const short* gk = qkv + tokbase + (long)(kv0 + krow) * (3 * DIM) + DIM + h * HEAD_DIM + kcol;
            GLL16(gk, &Ks[cb][(r * 256 + w * 64) * 8]);
            int kv = ((L >> 5) << 2) | ((L >> 1) & 3);
            int d  = ((L >> 3) & 3) * 16 + (L & 1) * 8;
            const short* gv = qkv + tokbase + (long)(kv0 + kv) * (3 * DIM) + 2 * DIM + h * HEAD_DIM + d;
            GLL16(gv, &Vs[cb][(r * 256 + w * 64) * 8]);
        }
    };

    stage(0, 0);
    int cur = 0;

    for (int kvt = 0; kvt < NN / 64; kvt++) {
        __syncthreads();
        if (kvt + 1 < NN / 64) stage(cur ^ 1, (kvt + 1) * 64);

        const int kswz = (lr & 7) << 3;
        f32x4 s[4];
#pragma unroll
        for (int n = 0; n < 4; n++) {
            int rowoff = (n * 16 + lr) * 64;
            bf16x8 kf0 = *(const bf16x8*)&Ks[cur][rowoff + ((lg * 8) ^ kswz)];
            bf16x8 kf1 = *(const bf16x8*)&Ks[cur][rowoff + ((32 + lg * 8) ^ kswz)];
            s[n] = {0.f, 0.f, 0.f, 0.f};
            s[n] = __builtin_amdgcn_mfma_f32_16x16x32_bf16(qf[0], kf0, s[n], 0, 0, 0);
            s[n] = __builtin_amdgcn_mfma_f32_16x16x32_bf16(qf[1], kf1, s[n], 0, 0, 0);
        }

        float corr[4];
#pragma unroll
        for (int j = 0; j < 4; j++) {
            float mx = fmaxf(fmaxf(s[0][j], s[1][j]), fmaxf(s[2][j], s[3][j]));
#pragma unroll
            for (int msk = 1; msk < 16; msk <<= 1) mx = fmaxf(mx, __shfl_xor(mx, msk));
            float mnew = fmaxf(mrow[j], mx);
            corr[j] = __expf(mrow[j] - mnew);
            mrow[j] = mnew;
            int prow = lg * 4 + j;
            int pswz = (prow & 7) << 3;
#pragma unroll
            for (int n = 0; n < 4; n++) {
                float p = __expf(s[n][j] - mnew);
                Ps[w][prow * 64 + ((n * 16 + lr) ^ pswz)] = f2bf(p);
            }
#pragma unroll
            for (int dn = 0; dn < 4; dn++) o[dn][j] *= corr[j];
        }

        i32x2 vrlo[2][4], vrhi[2][4];
#pragma unroll
        for (int kb = 0; kb < 2; kb++)
#pragma unroll
            for (int dn = 0; dn < 4; dn++) {
                unsigned voff = (unsigned)(size_t)&Vs[cur][(kb * 8 + lg * 2) * 256 + dn * 64 + lr];
                asm volatile("ds_read_b64_tr_b16 %0, %2\n\t"
                             "ds_read_b64_tr_b16 %1, %2 offset:512"
                             : "=&v"(vrlo[kb][dn]), "=&v"(vrhi[kb][dn])
                             : "v"(voff));
            }
        asm volatile("s_waitcnt lgkmcnt(0)" ::: "memory");
        __builtin_amdgcn_sched_barrier(0);

        f32x4 lsum = {0.f, 0.f, 0.f, 0.f};
#pragma unroll
        for (int kb = 0; kb < 2; kb++) {
            bf16x8 pf = *(const bf16x8*)&Ps[w][lr * 64 + ((kb * 32 + lg * 8) ^ ((lr & 7) << 3))];
            lsum = __builtin_amdgcn_mfma_f32_16x16x32_bf16(pf, ones, lsum, 0, 0, 0);
#pragma unroll
            for (int dn = 0; dn < 4; dn++) {
                union { i32x2 p[2]; bf16x8 v; } u;
                u.p[0] = vrlo[kb][dn];
                u.p[1] = vrhi[kb][dn];
                o[dn] = __builtin_amdgcn_mfma_f32_16x16x32_bf16(pf, u.v, o[dn], 0, 0, 0);
            }
        }
#pragma unroll
        for (int j = 0; j < 4; j++) lrow[j] = lrow[j] * corr[j] + lsum[j];

        cur ^= 1;
    }

#pragma unroll
    for (int j = 0; j < 4; j++) {
        float inv = 1.f / lrow[j];
        long tok = b * NN + qt * 64 + w * 16 + lg * 4 + j;
#pragma unroll
        for (int dn = 0; dn < 4; dn++)
            out[tok * DIM + h * HEAD_DIM + dn * 16 + lr] = f2bf(o[dn][j] * inv);
    }
}

// ---------------- launch ----------------
extern "C" void kernel_launch(void* const* d_in, const int* in_sizes, int n_in,
                              void* d_out, int out_size, void* d_ws, size_t ws_size,
                              hipStream_t stream) {
    const float* x       = (const float*)d_in[0];
    const float* ln1_w   = (const float*)d_in[1];
    const float* ln1_b   = (const float*)d_in[2];
    const float* qkv_w   = (const float*)d_in[3];
    const float* qkv_b   = (const float*)d_in[4];
    const float* proj_w  = (const float*)d_in[5];
    const float* proj_b  = (const float*)d_in[6];
    const float* ls1_g   = (const float*)d_in[7];
    const float* ln2_w   = (const float*)d_in[8];
    const float* ln2_b   = (const float*)d_in[9];
    const float* fc1_w   = (const float*)d_in[10];
    const float* fc1_b   = (const float*)d_in[11];
    const float* fc2_w   = (const float*)d_in[12];
    const float* fc2_b   = (const float*)d_in[13];
    const float* ls2_g   = (const float*)d_in[14];

    char* p = (char*)d_ws;
    short* wqkv   = (short*)p; p += (size_t)3 * DIM * DIM * 2;
    short* wproj  = (short*)p; p += (size_t)DIM * DIM * 2;
    short* wfc1   = (short*)p; p += (size_t)HIDDEN * DIM * 2;
    short* wfc2   = (short*)p; p += (size_t)DIM * HIDDEN * 2;
    short* h1     = (short*)p; p += (size_t)TOK * DIM * 2;
    short* qkvbuf = (short*)p; p += (size_t)TOK * 3 * DIM * 2;
    short* attno  = (short*)p; p += (size_t)TOK * DIM * 2;
    float* x2     = (float*)p; p += (size_t)TOK * DIM * 4;
    short* h2     = (short*)p; p += (size_t)TOK * DIM * 2;
    short* fc1o   = (short*)p; p += (size_t)TOK * HIDDEN * 2;

    {
        int n4;
        n4 = 3 * DIM * DIM / 4;
        cvt_kernel<<<dim3(2048), dim3(256), 0, stream>>>(qkv_w, wqkv, n4);
        n4 = DIM * DIM / 4;
        cvt_kernel<<<dim3(1024), dim3(256), 0, stream>>>(proj_w, wproj, n4);
        n4 = HIDDEN * DIM / 4;
        cvt_kernel<<<dim3(2048), dim3(256), 0, stream>>>(fc1_w, wfc1, n4);
        n4 = DIM * HIDDEN / 4;
        cvt_kernel<<<dim3(2048), dim3(256), 0, stream>>>(fc2_w, wfc2, n4);
    }

    // LN1
    ln_kernel<<<dim3(TOK), dim3(256), 0, stream>>>(x, ln1_w, ln1_b, h1);

    // QKV (8-phase 256²): M=4096, N=3072, K=1024 -> 16x12 = 192 blocks
    gemm8<1><<<dim3(192), dim3(512), 0, stream>>>(h1, wqkv, qkv_b, qkvbuf,
                                                  TOK, 3 * DIM, DIM, 12);

    // attention
    attn_kernel<<<dim3(NN / 64 * BB * HEADS), dim3(256), 0, stream>>>(qkvbuf, attno);

    // proj + residual + layer-scale -> x2 (fp32)
    gemm_bt<3><<<dim3(DIM / 128, TOK / 128), dim3(256), 0, stream>>>(
        attno, wproj, proj_b, x, ls1_g, x2, TOK, DIM, DIM);

    // LN2
    ln_kernel<<<dim3(TOK), dim3(256), 0, stream>>>(x2, ln2_w, ln2_b, h2);

    // FC1 + GELU (8-phase 256²): M=4096, N=4096, K=1024 -> 16x16 = 256 blocks
    gemm8<2><<<dim3(256), dim3(512), 0, stream>>>(h2, wfc1, fc1_b, fc1o,
                                                  TOK, HIDDEN, DIM, 16);

    // FC2 + residual + layer-scale -> d_out (fp32)
    gemm_bt<3><<<dim3(DIM / 128, TOK / 128), dim3(256), 0, stream>>>(
        fc1o, wfc2, fc2_b, x2, ls2_g, (float*)d_out, TOK, DIM, HIDDEN);
}

// Round 7
// 442.837 us; speedup vs baseline: 1.2510x; 1.0579x over previous
//
#include <hip/hip_runtime.h>

#define DIM 1024
#define HEADS 16
#define HEAD_DIM 64
#define HIDDEN 4096
#define BB 2
#define NN 2048
#define TOK (BB*NN)          // 4096 rows

typedef __attribute__((ext_vector_type(8))) short bf16x8;
typedef __attribute__((ext_vector_type(4))) float f32x4;
typedef __attribute__((ext_vector_type(2))) int i32x2;

__device__ inline short f2bf(float f) {
    unsigned u = __float_as_uint(f);
    unsigned r = (u + 0x7fff + ((u >> 16) & 1)) >> 16;
    return (short)r;
}

#define GLL16(g, l)                                                          \
    __builtin_amdgcn_global_load_lds(                                        \
        (const __attribute__((address_space(1))) void*)(g),                  \
        (__attribute__((address_space(3))) void*)(l), 16, 0, 0)

#define BARRIER() do { asm volatile("" ::: "memory");                        \
    __builtin_amdgcn_s_barrier();                                            \
    asm volatile("" ::: "memory"); } while (0)

// ---------------- fp32 -> bf16 convert ----------------
__global__ void cvt_kernel(const float* __restrict__ in, short* __restrict__ out, int n4) {
    int i = blockIdx.x * blockDim.x + threadIdx.x;
    int stride = gridDim.x * blockDim.x;
    for (; i < n4; i += stride) {
        float4 v = ((const float4*)in)[i];
        short4 o;
        o.x = f2bf(v.x); o.y = f2bf(v.y); o.z = f2bf(v.z); o.w = f2bf(v.w);
        ((short4*)out)[i] = o;
    }
}

// ---------------- LayerNorm (per-row, DIM=1024) -> bf16 ----------------
__global__ __launch_bounds__(256) void ln_kernel(const float* __restrict__ x,
                                                 const float* __restrict__ w,
                                                 const float* __restrict__ b,
                                                 short* __restrict__ out) {
    const int row = blockIdx.x;
    const int t = threadIdx.x;
    float4 v = ((const float4*)(x + (long)row * DIM))[t];
    float s = v.x + v.y + v.z + v.w;
    float ss = v.x * v.x + v.y * v.y + v.z * v.z + v.w * v.w;
#pragma unroll
    for (int m = 1; m < 64; m <<= 1) {
        s += __shfl_xor(s, m);
        ss += __shfl_xor(ss, m);
    }
    __shared__ float rs[4], rss[4];
    int wv = t >> 6;
    if ((t & 63) == 0) { rs[wv] = s; rss[wv] = ss; }
    __syncthreads();
    s = rs[0] + rs[1] + rs[2] + rs[3];
    ss = rss[0] + rss[1] + rss[2] + rss[3];
    float mean = s * (1.f / DIM);
    float var = ss * (1.f / DIM) - mean * mean;
    float rstd = rsqrtf(var + 1e-5f);
    float4 wv4 = ((const float4*)w)[t];
    float4 bv4 = ((const float4*)b)[t];
    short4 o;
    o.x = f2bf((v.x - mean) * rstd * wv4.x + bv4.x);
    o.y = f2bf((v.y - mean) * rstd * wv4.y + bv4.y);
    o.z = f2bf((v.z - mean) * rstd * wv4.z + bv4.z);
    o.w = f2bf((v.w - mean) * rstd * wv4.w + bv4.w);
    ((short4*)(out + (long)row * DIM))[t] = o;
}

// ============ BMx256 8-phase GEMM, deep prefetch (T1..T5) =================
// C[M,N] = A[M,K] @ Bt[N,K]^T + bias. BM in {256,128}; BN=256; BK=64.
// 8 waves (2 x 4), wave tile (BM/2) x 64, acc[BM/32][4].
// A LDS: linear [BM][64] per buffer, staged whole (ALOADS=BM/64 per thread).
// B LDS: two halves per buffer; half h phys row p -> global col
//        (p>>5)*64 + h*32 + (p&31)  (interleaved 32-col groups).
// Swizzle (T2): element offset ^= (row&7)<<3 on read; staging pre-swizzles
// the GLOBAL source column, LDS dest stays linear (rule #21).
// Deep prefetch: restage each buffer at its earliest-free phase:
//   ph2: B[0][0]  ph3: B[0][1]  ph4: A[0]   (tile 2i+2)
//   ph6: B[1][0]  ph7: B[1][1]  ph8: A[1]   (tile 2i+3)
// vmcnt(4+ALOADS) at ph4/ph8 drains loads issued >=4 phases earlier.
// EPI: 1 qkv (scale cols<DIM by 0.125, bf16 out); 2 gelu (bf16 out);
//      3 residual + layer-scale (fp32 out).
template <int EPI, int BM>
__global__ __launch_bounds__(512, 2) void gemm8(const short* __restrict__ A,
                                                const short* __restrict__ Bt,
                                                const float* __restrict__ bias,
                                                const float* __restrict__ resid,
                                                const float* __restrict__ gamma,
                                                void* __restrict__ Cout,
                                                int M, int N, int K, int nbx) {
    constexpr int ALOADS = BM / 64;      // A stage loads per thread (4 or 2)
    constexpr int MMP = BM / 64;         // m-subtiles per phase (4 or 2)
    constexpr int AR = BM / 32;          // acc rows (8 or 4)

    __shared__ __align__(16) short As[2][BM * 64];
    __shared__ __align__(16) short Bs[2][2][128 * 64];

    const int t = threadIdx.x;
    const int w = t >> 6, l = t & 63, lr = l & 15, lg = l >> 4;
    const int wr = w >> 2, wc = w & 3;

    // T1: bijective XCD swizzle (all grids here are multiples of 8)
    const int nwg = gridDim.x;
    const int id = blockIdx.x;
    const int r = (id & 7) * (nwg >> 3) + (id >> 3);
    const int by = r / nbx, bx = r % nbx;
    const int rowBase = by * BM, colBase = bx * 256;

    f32x4 acc[AR][4];
#pragma unroll
    for (int m = 0; m < AR; m++)
#pragma unroll
        for (int n = 0; n < 4; n++) acc[m][n] = {0.f, 0.f, 0.f, 0.f};

    bf16x8 afr[MMP][2];
    bf16x8 bfr[4][2];

    const int NT = K >> 6;
    const int ITERS = NT >> 1;

    auto stageA = [&](int buf, int tile) {
        const long k0 = (long)tile * 64;
#pragma unroll
        for (int j = 0; j < ALOADS; j++) {
            int L = j * 512 + t;
            int p = L >> 3;                       // global row offset (linear)
            int colS = ((L & 7) ^ (p & 7)) << 3;  // pre-swizzled source col
            const short* g = A + (long)(rowBase + p) * K + k0 + colS;
            GLL16(g, &As[buf][(j * 512 + w * 64) * 8]);
        }
    };
    auto stageBh = [&](int buf, int h, int tile) {
        const long k0 = (long)tile * 64;
#pragma unroll
        for (int j = 0; j < 2; j++) {
            int L = j * 512 + t;
            int p = L >> 3;
            int gcol = ((p >> 5) << 6) + (h << 5) + (p & 31);
            int colS = ((L & 7) ^ (p & 7)) << 3;
            const short* g = Bt + (long)(colBase + gcol) * K + k0 + colS;
            GLL16(g, &Bs[buf][h][(j * 512 + w * 64) * 8]);
        }
    };
    auto ldA = [&](int buf, int mh) {
#pragma unroll
        for (int mm = 0; mm < MMP; mm++) {
            int phys = wr * (BM / 2) + mh * (BM / 4) + mm * 16 + lr;
            int base = phys * 64, sw = (phys & 7) << 3;
#pragma unroll
            for (int ks = 0; ks < 2; ks++)
                afr[mm][ks] = *(const bf16x8*)&As[buf][base + ((ks * 32 + lg * 8) ^ sw)];
        }
    };
    auto ldB = [&](int buf, int nh) {
#pragma unroll
        for (int nn = 0; nn < 2; nn++) {
            int phys = wc * 32 + nn * 16 + lr;
            int base = phys * 64, sw = (phys & 7) << 3;
#pragma unroll
            for (int ks = 0; ks < 2; ks++)
                bfr[nh * 2 + nn][ks] = *(const bf16x8*)&Bs[buf][nh][base + ((ks * 32 + lg * 8) ^ sw)];
        }
    };
    auto mfmaQ = [&](int mh, int nh) {
        __builtin_amdgcn_s_setprio(1);
#pragma unroll
        for (int ks = 0; ks < 2; ks++)
#pragma unroll
            for (int mm = 0; mm < MMP; mm++)
#pragma unroll
                for (int nn = 0; nn < 2; nn++)
                    acc[mh * MMP + mm][nh * 2 + nn] = __builtin_amdgcn_mfma_f32_16x16x32_bf16(
                        afr[mm][ks], bfr[nh * 2 + nn][ks], acc[mh * MMP + mm][nh * 2 + nn], 0, 0, 0);
        __builtin_amdgcn_s_setprio(0);
    };
    auto waitVM = [&]() {
        if constexpr (BM == 256) asm volatile("s_waitcnt vmcnt(8)" ::: "memory");
        else                     asm volatile("s_waitcnt vmcnt(6)" ::: "memory");
    };

    // prologue: tile0 then tile1; drain tile0, keep tile1 in flight
    stageBh(0, 0, 0); stageBh(0, 1, 0); stageA(0, 0);
    stageBh(1, 0, 1); stageBh(1, 1, 1); stageA(1, 1);
    waitVM();
    BARRIER();

    for (int i = 0; i < ITERS; i++) {
        const bool more = (i < ITERS - 1);
        // ph1: quadrant (m0,n0) of tile 2i (buf0)
        ldA(0, 0); ldB(0, 0);
        BARRIER(); mfmaQ(0, 0); BARRIER();
        // ph2
        ldB(0, 1);
        if (more) stageBh(0, 0, 2 * i + 2);
        BARRIER(); mfmaQ(0, 1); BARRIER();
        // ph3
        ldA(0, 1);
        if (more) stageBh(0, 1, 2 * i + 2);
        BARRIER(); mfmaQ(1, 0); BARRIER();
        // ph4: stage A0, counted wait (drains tile 2i+1 = prev ph6-8)
        if (more) { stageA(0, 2 * i + 2); waitVM(); }
        else      { asm volatile("s_waitcnt vmcnt(0)" ::: "memory"); }
        BARRIER(); mfmaQ(1, 1); BARRIER();
        // ph5: quadrant (m0,n0) of tile 2i+1 (buf1)
        ldA(1, 0); ldB(1, 0);
        BARRIER(); mfmaQ(0, 0); BARRIER();
        // ph6
        ldB(1, 1);
        if (more) stageBh(1, 0, 2 * i + 3);
        BARRIER(); mfmaQ(0, 1); BARRIER();
        // ph7
        ldA(1, 1);
        if (more) stageBh(1, 1, 2 * i + 3);
        BARRIER(); mfmaQ(1, 0); BARRIER();
        // ph8: stage A1, counted wait (drains tile 2i+2 = ph2-4)
        if (more) { stageA(1, 2 * i + 3); waitVM(); }
        else      { asm volatile("s_waitcnt vmcnt(0)" ::: "memory"); }
        BARRIER(); mfmaQ(1, 1); BARRIER();
    }

    // epilogue
#pragma unroll
    for (int n = 0; n < 4; n++) {
        int col = colBase + wc * 64 + n * 16 + lr;
        float bs = bias[col];
        float gm = (EPI == 3) ? gamma[col] : 0.f;
#pragma unroll
        for (int m = 0; m < AR; m++) {
            int row0 = rowBase + wr * (BM / 2) + m * 16 + lg * 4;
#pragma unroll
            for (int j = 0; j < 4; j++) {
                int row = row0 + j;
                float v = acc[m][n][j] + bs;
                if (EPI == 1) { if (col < DIM) v *= 0.125f; }
                if (EPI == 2) { v = 0.5f * v * (1.f + erff(v * 0.70710678118f)); }
                if (EPI == 3) {
                    float o = resid[(long)row * N + col] + v * gm;
                    ((float*)Cout)[(long)row * N + col] = o;
                } else {
                    ((short*)Cout)[(long)row * N + col] = f2bf(v);
                }
            }
        }
    }
}

// ---------------- Flash attention (swizzled K/P, tr-read V, dbuf) ---------
__global__ __launch_bounds__(256) void attn_kernel(const short* __restrict__ qkv,
                                                   short* __restrict__ out) {
    const int id = blockIdx.x;
    const int rank = (id & 7) * 128 + (id >> 3);
    const int bh = rank >> 5, qt = rank & 31;
    const int b = bh >> 4, h = bh & 15;
    const int t = threadIdx.x;
    const int w = t >> 6, l = t & 63, lr = l & 15, lg = l >> 4;

    __shared__ __align__(16) short Ks[2][4096];
    __shared__ __align__(16) short Vs[2][4096];
    __shared__ __align__(16) short Ps[4][1024];

    bf16x8 qf[2];
    {
        const int qtok = b * NN + qt * 64 + w * 16 + lr;
        const short* qp = qkv + (long)qtok * (3 * DIM) + h * HEAD_DIM;
        qf[0] = *(const bf16x8*)(qp + lg * 8);
        qf[1] = *(const bf16x8*)(qp + 32 + lg * 8);
    }

    bf16x8 ones;
#pragma unroll
    for (int i = 0; i < 8; i++) ones[i] = (short)0x3F80;

    f32x4 o[4];
#pragma unroll
    for (int dn = 0; dn < 4; dn++) o[dn] = {0.f, 0.f, 0.f, 0.f};
    float mrow[4] = {-1e30f, -1e30f, -1e30f, -1e30f};
    float lrow[4] = {0.f, 0.f, 0.f, 0.f};

    const long tokbase = (long)(b * NN) * (3 * DIM);

    auto stage = [&](int cb, int kv0) {
#pragma unroll
        for (int r = 0; r < 2; r++) {
            int L = r * 256 + t;
            int krow = L >> 3;
            int kcol = ((L & 7) * 8) ^ ((krow & 7) << 3);
            const short* gk = qkv + tokbase + (long)(kv0 + krow) * (3 * DIM) + DIM + h * HEAD_DIM + kcol;
            GLL16(gk, &Ks[cb][(r * 256 + w * 64) * 8]);
            int kv = ((L >> 5) << 2) | ((L >> 1) & 3);
            int d  = ((L >> 3) & 3) * 16 + (L & 1) * 8;
            const short* gv = qkv + tokbase + (long)(kv0 + kv) * (3 * DIM) + 2 * DIM + h * HEAD_DIM + d;
            GLL16(gv, &Vs[cb][(r * 256 + w * 64) * 8]);
        }
    };

    stage(0, 0);
    int cur = 0;

    for (int kvt = 0; kvt < NN / 64; kvt++) {
        __syncthreads();
        if (kvt + 1 < NN / 64) stage(cur ^ 1, (kvt + 1) * 64);

        const int kswz = (lr & 7) << 3;
        f32x4 s[4];
#pragma unroll
        for (int n = 0; n < 4; n++) {
            int rowoff = (n * 16 + lr) * 64;
            bf16x8 kf0 = *(const bf16x8*)&Ks[cur][rowoff + ((lg * 8) ^ kswz)];
            bf16x8 kf1 = *(const bf16x8*)&Ks[cur][rowoff + ((32 + lg * 8) ^ kswz)];
            s[n] = {0.f, 0.f, 0.f, 0.f};
            s[n] = __builtin_amdgcn_mfma_f32_16x16x32_bf16(qf[0], kf0, s[n], 0, 0, 0);
            s[n] = __builtin_amdgcn_mfma_f32_16x16x32_bf16(qf[1], kf1, s[n], 0, 0, 0);
        }

        float corr[4];
#pragma unroll
        for (int j = 0; j < 4; j++) {
            float mx = fmaxf(fmaxf(s[0][j], s[1][j]), fmaxf(s[2][j], s[3][j]));
#pragma unroll
            for (int msk = 1; msk < 16; msk <<= 1) mx = fmaxf(mx, __shfl_xor(mx, msk));
            float mnew = fmaxf(mrow[j], mx);
            corr[j] = __expf(mrow[j] - mnew);
            mrow[j] = mnew;
            int prow = lg * 4 + j;
            int pswz = (prow & 7) << 3;
#pragma unroll
            for (int n = 0; n < 4; n++) {
                float p = __expf(s[n][j] - mnew);
                Ps[w][prow * 64 + ((n * 16 + lr) ^ pswz)] = f2bf(p);
            }
#pragma unroll
            for (int dn = 0; dn < 4; dn++) o[dn][j] *= corr[j];
        }

        i32x2 vrlo[2][4], vrhi[2][4];
#pragma unroll
        for (int kb = 0; kb < 2; kb++)
#pragma unroll
            for (int dn = 0; dn < 4; dn++) {
                unsigned voff = (unsigned)(size_t)&Vs[cur][(kb * 8 + lg * 2) * 256 + dn * 64 + lr];
                asm volatile("ds_read_b64_tr_b16 %0, %2\n\t"
                             "ds_read_b64_tr_b16 %1, %2 offset:512"
                             : "=&v"(vrlo[kb][dn]), "=&v"(vrhi[kb][dn])
                             : "v"(voff));
            }
        asm volatile("s_waitcnt lgkmcnt(0)" ::: "memory");
        __builtin_amdgcn_sched_barrier(0);

        f32x4 lsum = {0.f, 0.f, 0.f, 0.f};
#pragma unroll
        for (int kb = 0; kb < 2; kb++) {
            bf16x8 pf = *(const bf16x8*)&Ps[w][lr * 64 + ((kb * 32 + lg * 8) ^ ((lr & 7) << 3))];
            lsum = __builtin_amdgcn_mfma_f32_16x16x32_bf16(pf, ones, lsum, 0, 0, 0);
#pragma unroll
            for (int dn = 0; dn < 4; dn++) {
                union { i32x2 p[2]; bf16x8 v; } u;
                u.p[0] = vrlo[kb][dn];
                u.p[1] = vrhi[kb][dn];
                o[dn] = __builtin_amdgcn_mfma_f32_16x16x32_bf16(pf, u.v, o[dn], 0, 0, 0);
            }
        }
#pragma unroll
        for (int j = 0; j < 4; j++) lrow[j] = lrow[j] * corr[j] + lsum[j];

        cur ^= 1;
    }

#pragma unroll
    for (int j = 0; j < 4; j++) {
        float inv = 1.f / lrow[j];
        long tok = b * NN + qt * 64 + w * 16 + lg * 4 + j;
#pragma unroll
        for (int dn = 0; dn < 4; dn++)
            out[tok * DIM + h * HEAD_DIM + dn * 16 + lr] = f2bf(o[dn][j] * inv);
    }
}

// ---------------- launch ----------------
extern "C" void kernel_launch(void* const* d_in, const int* in_sizes, int n_in,
                              void* d_out, int out_size, void* d_ws, size_t ws_size,
                              hipStream_t stream) {
    const float* x       = (const float*)d_in[0];
    const float* ln1_w   = (const float*)d_in[1];
    const float* ln1_b   = (const float*)d_in[2];
    const float* qkv_w   = (const float*)d_in[3];
    const float* qkv_b   = (const float*)d_in[4];
    const float* proj_w  = (const float*)d_in[5];
    const float* proj_b  = (const float*)d_in[6];
    const float* ls1_g   = (const float*)d_in[7];
    const float* ln2_w   = (const float*)d_in[8];
    const float* ln2_b   = (const float*)d_in[9];
    const float* fc1_w   = (const float*)d_in[10];
    const float* fc1_b   = (const float*)d_in[11];
    const float* fc2_w   = (const float*)d_in[12];
    const float* fc2_b   = (const float*)d_in[13];
    const float* ls2_g   = (const float*)d_in[14];

    char* p = (char*)d_ws;
    short* wqkv   = (short*)p; p += (size_t)3 * DIM * DIM * 2;
    short* wproj  = (short*)p; p += (size_t)DIM * DIM * 2;
    short* wfc1   = (short*)p; p += (size_t)HIDDEN * DIM * 2;
    short* wfc2   = (short*)p; p += (size_t)DIM * HIDDEN * 2;
    short* h1     = (short*)p; p += (size_t)TOK * DIM * 2;
    short* qkvbuf = (short*)p; p += (size_t)TOK * 3 * DIM * 2;
    short* attno  = (short*)p; p += (size_t)TOK * DIM * 2;
    float* x2     = (float*)p; p += (size_t)TOK * DIM * 4;
    short* h2     = (short*)p; p += (size_t)TOK * DIM * 2;
    short* fc1o   = (short*)p; p += (size_t)TOK * HIDDEN * 2;

    {
        int n4;
        n4 = 3 * DIM * DIM / 4;
        cvt_kernel<<<dim3(2048), dim3(256), 0, stream>>>(qkv_w, wqkv, n4);
        n4 = DIM * DIM / 4;
        cvt_kernel<<<dim3(1024), dim3(256), 0, stream>>>(proj_w, wproj, n4);
        n4 = HIDDEN * DIM / 4;
        cvt_kernel<<<dim3(2048), dim3(256), 0, stream>>>(fc1_w, wfc1, n4);
        n4 = DIM * HIDDEN / 4;
        cvt_kernel<<<dim3(2048), dim3(256), 0, stream>>>(fc2_w, wfc2, n4);
    }

    // LN1
    ln_kernel<<<dim3(TOK), dim3(256), 0, stream>>>(x, ln1_w, ln1_b, h1);

    // QKV: 256x256 tiles, 16x12 = 192 blocks
    gemm8<1, 256><<<dim3(192), dim3(512), 0, stream>>>(
        h1, wqkv, qkv_b, nullptr, nullptr, qkvbuf, TOK, 3 * DIM, DIM, 12);

    // attention
    attn_kernel<<<dim3(NN / 64 * BB * HEADS), dim3(256), 0, stream>>>(qkvbuf, attno);

    // proj + residual + layer-scale -> x2 (fp32): 128x256 tiles, 32x4 = 128 blocks
    gemm8<3, 128><<<dim3(128), dim3(512), 0, stream>>>(
        attno, wproj, proj_b, x, ls1_g, x2, TOK, DIM, DIM, 4);

    // LN2
    ln_kernel<<<dim3(TOK), dim3(256), 0, stream>>>(x2, ln2_w, ln2_b, h2);

    // FC1 + GELU: 256x256 tiles, 16x16 = 256 blocks
    gemm8<2, 256><<<dim3(256), dim3(512), 0, stream>>>(
        h2, wfc1, fc1_b, nullptr, nullptr, fc1o, TOK, HIDDEN, DIM, 16);

    // FC2 + residual + layer-scale -> d_out (fp32): 128x256 tiles, 128 blocks
    gemm8<3, 128><<<dim3(128), dim3(512), 0, stream>>>(
        fc1o, wfc2, fc2_b, x2, ls2_g, (float*)d_out, TOK, DIM, HIDDEN, 4);
}